// Round 3
// baseline (605.131 us; speedup 1.0000x reference)
//
#include <hip/hip_runtime.h>
#include <hip/hip_bf16.h>
#include <math.h>

// ---------------------------------------------------------------------------
// FeatureAttnNet v3 for MI355X (gfx950)
//
// score[b,f] = Y0[b,f] + sum_c cmd[b,c]*Yc[b,f], Y = X @ WKfold^T (5 rows/f,
// BN-folded; additive BN term cancels in softmax). V-contraction fused with
// per-(b,f) softmax weights. fused_attn v3: wave-independent (NO barriers),
// 8 waves/CU, A-fragments loaded once per half and reused by both GEMMs,
// B-fragments streamed from global (L1/L2-resident weights), wgt via 1KB/wave
// LDS strip (intra-wave exchange only).
// ---------------------------------------------------------------------------

typedef float  f32x4   __attribute__((ext_vector_type(4)));
typedef float  f32x16  __attribute__((ext_vector_type(16)));
typedef __bf16 bf16x4  __attribute__((ext_vector_type(4)));
typedef __bf16 bf16x8  __attribute__((ext_vector_type(8)));

#define MFMA16(A, B, C) __builtin_amdgcn_mfma_f32_16x16x32_bf16((A), (B), (C), 0, 0, 0)
#define MFMA32(A, B, C) __builtin_amdgcn_mfma_f32_32x32x16_bf16((A), (B), (C), 0, 0, 0)

#define EPSV 1e-5f

// ---- workspace layout (bytes) ----
#define WS_WV    0x000000u   // 2048*256 bf16 = 1 MiB  [Wvz;Wvh]
#define WS_WKF   0x100000u   // 2*96*256 bf16 = 96 KiB folded K weights (zero-padded)
#define WS_G     0x120000u   // 2*256*256 f32 = 512 KiB
#define WS_CS    0x1A0000u   // 2*256 f32 colsums (zeroed)
#define WS_CMDP  0x1A0800u   // 64*14 f32 cmd partials
#define WS_T     0x1A1800u   // 2048 f32
#define WS_U     0x1A3800u   // 2048 f32
#define WS_WQ2   0x1A5800u   // 256 f32
#define WS_C0    0x1A5C00u   // 64 f32
#define WS_GPART 0x1B0000u   // partial Gram buffers
#define WS_NEED256 (WS_GPART + 256u * 65536u * 4u)   // ~68.8 MB
#define WS_NEED128 (WS_GPART + 128u * 65536u * 4u)   // ~35.3 MB

// ---------------------------------------------------------------------------
__global__ void prepV(const float* __restrict__ Wvz, const float* __restrict__ Wvh,
                      __bf16* __restrict__ WV)
{
    int t = blockIdx.x * 256 + threadIdx.x;     // 0..131071
    int e = t * 4;
    const float* src = (e < 262144) ? (Wvz + e) : (Wvh + (e - 262144));
    float4 a = *(const float4*)src;
    bf16x4 v = { (__bf16)a.x, (__bf16)a.y, (__bf16)a.z, (__bf16)a.w };
    *(bf16x4*)(WV + e) = v;
}

// ---------------------------------------------------------------------------
__global__ void cmd_stats(const float4* __restrict__ cmd, float* __restrict__ CMDP)
{
    __shared__ float sm[4][14];
    const int tid = threadIdx.x, blk = blockIdx.x;
    float v[14];
#pragma unroll
    for (int k = 0; k < 14; ++k) v[k] = 0.f;
#pragma unroll
    for (int i = 0; i < 4; ++i) {
        float4 c = cmd[blk * 1024 + i * 256 + tid];
        v[0] += c.x;  v[1] += c.y;  v[2] += c.z;  v[3] += c.w;
        v[4] += c.x*c.x; v[5] += c.x*c.y; v[6] += c.x*c.z; v[7] += c.x*c.w;
        v[8] += c.y*c.y; v[9] += c.y*c.z; v[10] += c.y*c.w;
        v[11] += c.z*c.z; v[12] += c.z*c.w; v[13] += c.w*c.w;
    }
#pragma unroll
    for (int k = 0; k < 14; ++k) {
        float s = v[k];
#pragma unroll
        for (int off = 32; off; off >>= 1) s += __shfl_xor(s, off);
        if ((tid & 63) == 0) sm[tid >> 6][k] = s;
    }
    __syncthreads();
    if (tid < 14) CMDP[blk * 14 + tid] = sm[0][tid] + sm[1][tid] + sm[2][tid] + sm[3][tid];
}

// ---------------------------------------------------------------------------
// Gram: block covers iters*32 rows of X from k0; writes per-block partial or
// atomics into the per-matrix accumulator.
__global__ __launch_bounds__(512, 2) void gram_kernel(const float* __restrict__ feat,
        const float* __restrict__ hid, float* __restrict__ dst, float* __restrict__ CS,
        int chunk_bits, int iters, int atomic_out)
{
    __shared__ __bf16 T[256 * 40];
    const int tid  = threadIdx.x;
    const int blk  = blockIdx.x;
    const int mat  = blk >> chunk_bits;
    const int chunk = blk & ((1 << chunk_bits) - 1);
    const float* X = mat ? hid : feat;
    float* cs = CS + mat * 256;
    const int k0   = chunk * (iters * 32);
    const int wid  = tid >> 6, lane = tid & 63, quad = lane >> 4, l15 = lane & 15;
    const int c    = tid & 255;
    const int t8   = tid >> 8;

    f32x4 acc[2][16];
#pragma unroll
    for (int mt = 0; mt < 2; ++mt)
#pragma unroll
        for (int nt = 0; nt < 16; ++nt) acc[mt][nt] = (f32x4){0.f, 0.f, 0.f, 0.f};

    float clsum = 0.f;
    for (int it = 0; it < iters; ++it) {
        __syncthreads();
        const int kb = k0 + it * 32;
#pragma unroll
        for (int i = 0; i < 16; ++i) {
            int k = t8 + 2 * i;
            float x = X[(size_t)(kb + k) * 256 + c];
            clsum += x;
            T[c * 40 + k] = (__bf16)x;
        }
        __syncthreads();
        bf16x8 a0 = *(const bf16x8*)&T[(wid * 32 +      l15) * 40 + quad * 8];
        bf16x8 a1 = *(const bf16x8*)&T[(wid * 32 + 16 + l15) * 40 + quad * 8];
#pragma unroll
        for (int nt = 0; nt < 16; ++nt) {
            bf16x8 b = *(const bf16x8*)&T[(nt * 16 + l15) * 40 + quad * 8];
            acc[0][nt] = MFMA16(a0, b, acc[0][nt]);
            acc[1][nt] = MFMA16(a1, b, acc[1][nt]);
        }
    }
    atomicAdd(&cs[c], clsum);
    float* outp = atomic_out ? (dst + (size_t)mat * 65536) : (dst + (size_t)blk * 65536);
#pragma unroll
    for (int mt = 0; mt < 2; ++mt)
#pragma unroll
        for (int nt = 0; nt < 16; ++nt)
#pragma unroll
            for (int r = 0; r < 4; ++r) {
                int gi = wid * 32 + mt * 16 + quad * 4 + r;
                int gj = nt * 16 + l15;
                if (atomic_out) atomicAdd(&outp[gi * 256 + gj], acc[mt][nt][r]);
                else            outp[gi * 256 + gj] = acc[mt][nt][r];
            }
}

__global__ void gram_reduce(const float* __restrict__ Gpart, float* __restrict__ G,
                            int npart)
{
    int o = blockIdx.x * 256 + threadIdx.x;   // 512x256 = 131072 outputs
    int mat = o >> 16, e = o & 65535;
    const float* p = Gpart + (size_t)mat * npart * 65536 + e;
    float s = 0.f;
    for (int c = 0; c < npart; ++c) s += p[(size_t)c * 65536];
    G[o] = s;
}

// ---------------------------------------------------------------------------
__global__ void rowstats(const float* __restrict__ Wkz, const float* __restrict__ Wkh,
        const float* __restrict__ G, const float* __restrict__ CS,
        float* __restrict__ Tout, float* __restrict__ Uout)
{
    const int blk = blockIdx.x;               // 256 blocks
    const int mat = blk >> 7, jg = blk & 127;
    const float* Wsrc = (mat ? Wkh : Wkz) + (size_t)jg * 8 * 256;
    const float* Gm = G + (size_t)mat * 65536;
    const float* cs = CS + mat * 256;
    __shared__ float wlT[256 * 8];
    __shared__ float red[4][16];
    const int tid = threadIdx.x, wid = tid >> 6, lane = tid & 63;
#pragma unroll
    for (int jj = 0; jj < 8; ++jj) wlT[tid * 8 + jj] = Wsrc[jj * 256 + tid];
    __syncthreads();
    float inner[8];
#pragma unroll
    for (int jj = 0; jj < 8; ++jj) inner[jj] = 0.f;
    for (int r = 0; r < 256; ++r) {
        float g = Gm[r * 256 + tid];
        float4 w0 = *(const float4*)&wlT[r * 8];
        float4 w1 = *(const float4*)&wlT[r * 8 + 4];
        inner[0] = fmaf(w0.x, g, inner[0]); inner[1] = fmaf(w0.y, g, inner[1]);
        inner[2] = fmaf(w0.z, g, inner[2]); inner[3] = fmaf(w0.w, g, inner[3]);
        inner[4] = fmaf(w1.x, g, inner[4]); inner[5] = fmaf(w1.y, g, inner[5]);
        inner[6] = fmaf(w1.z, g, inner[6]); inner[7] = fmaf(w1.w, g, inner[7]);
    }
    float cst = cs[tid];
#pragma unroll
    for (int jj = 0; jj < 8; ++jj) {
        float wme = wlT[tid * 8 + jj];
        float p = wme * inner[jj];
        float u = wme * cst;
#pragma unroll
        for (int off = 32; off; off >>= 1) { p += __shfl_xor(p, off); u += __shfl_xor(u, off); }
        if (lane == 0) { red[wid][jj] = p; red[wid][jj + 8] = u; }
    }
    __syncthreads();
    if (tid < 16) {
        float s = red[0][tid] + red[1][tid] + red[2][tid] + red[3][tid];
        int jj = tid & 7;
        int j = mat * 1024 + jg * 8 + jj;
        if (tid < 8) Tout[j] = s; else Uout[j] = s;
    }
}

// ---------------------------------------------------------------------------
__global__ void finalize_kernel(const float* __restrict__ Wq,
        const float* __restrict__ gQ, const float* __restrict__ bQ,
        const float* __restrict__ gK, const float* __restrict__ bK,
        const float* __restrict__ CMDP, const float* __restrict__ T,
        const float* __restrict__ U, float* __restrict__ Wq2, float* __restrict__ C0)
{
    __shared__ float s14[14];
    const int d = threadIdx.x;
    if (d < 14) {
        float s = 0.f;
        for (int b = 0; b < 64; ++b) s += CMDP[b * 14 + d];
        s14[d] = s;
    }
    __syncthreads();
    float s4[4] = { s14[0], s14[1], s14[2], s14[3] };
    float gc[4][4];
    gc[0][0] = s14[4];
    gc[0][1] = gc[1][0] = s14[5];
    gc[0][2] = gc[2][0] = s14[6];
    gc[0][3] = gc[3][0] = s14[7];
    gc[1][1] = s14[8];
    gc[1][2] = gc[2][1] = s14[9];
    gc[1][3] = gc[3][1] = s14[10];
    gc[2][2] = s14[11];
    gc[2][3] = gc[3][2] = s14[12];
    gc[3][3] = s14[13];
    float wq[4];
#pragma unroll
    for (int c = 0; c < 4; ++c) wq[c] = Wq[d * 4 + c];
    const float invB = 1.0f / 65536.0f;
    float mQ = (wq[0]*s4[0] + wq[1]*s4[1] + wq[2]*s4[2] + wq[3]*s4[3]) * invB;
    float eq2 = 0.f;
#pragma unroll
    for (int c = 0; c < 4; ++c)
#pragma unroll
        for (int c2 = 0; c2 < 4; ++c2) eq2 += wq[c] * wq[c2] * gc[c][c2];
    eq2 *= invB;
    float vQ  = eq2 - mQ * mQ;
    float aQ  = gQ[d] / sqrtf(vQ + EPSV);
    float bQv = bQ[d] - mQ * aQ;
    float S2 = 0.f, S1 = 0.f;
#pragma unroll
    for (int f = 0; f < 32; ++f) { S2 += T[f * 64 + d]; S1 += U[f * 64 + d]; }
    const float invBF = 1.0f / (65536.0f * 32.0f);
    float e2 = S2 * invBF, mK = S1 * invBF;
    float vK = e2 - mK * mK;
    float aK = gK[d] / sqrtf(vK + EPSV);
    float c1 = aQ * aK * 0.125f;      // 1/sqrt(64) folded in
    C0[d] = bQv * aK * 0.125f;
#pragma unroll
    for (int c = 0; c < 4; ++c) Wq2[d * 4 + c] = c1 * wq[c];
}

// ---------------------------------------------------------------------------
// WKF[h][r = c*16 + fl][k] = sum_d coef_c[d]*W_h[fl*64+d][k]; rows 80..95 = 0.
__global__ void foldK(const float* __restrict__ Wkz, const float* __restrict__ Wkh,
                      const float* __restrict__ Wq2, const float* __restrict__ C0,
                      __bf16* __restrict__ WKF)
{
    const int blk = blockIdx.x;               // 192
    const int h = blk / 96, rr = blk % 96;
    const int k = threadIdx.x;
    float s = 0.f;
    if (rr < 80) {
        const int c = rr >> 4, fl = rr & 15;
        const float* Wsrc = (h ? Wkh : Wkz) + (size_t)fl * 64 * 256;
        for (int d = 0; d < 64; ++d) {
            float coef = (c == 0) ? C0[d] : Wq2[d * 4 + (c - 1)];
            s = fmaf(coef, Wsrc[d * 256 + k], s);
        }
    }
    WKF[(size_t)(h * 96 + rr) * 256 + k] = (__bf16)s;
}

// ---------------------------------------------------------------------------
// Fused attention v3: 512 blocks x 256 threads; wave = 32 rows; NO barriers.
// Per half h: load a2[16] (X rows, 32x32x16 A-layout) once; phase-1 score
// MFMA vs WKF (96 rows, global B-frags); exp -> wgt in per-wave LDS strip;
// phase-2 V GEMM (global B-frags) weighted into s_acc.
__global__ __launch_bounds__(256, 2) void fused_attn(
        const float* __restrict__ feat, const float* __restrict__ hid,
        const float4* __restrict__ cmd, const __bf16* __restrict__ WV,
        const __bf16* __restrict__ WKF, float* __restrict__ out)
{
    __shared__ __bf16 WGT[4][16][32];         // [wave][f-local][row] 4 KiB
    const int tid  = threadIdx.x;
    const int wid  = tid >> 6, lane = tid & 63;
    const int l5   = lane & 31, hi = lane >> 5;
    const int fl   = l5 & 15;
    const bool low = (l5 < 16);
    const int wrow = (blockIdx.x << 7) + (wid << 5);   // wave's first row

    float l_i[16];
    f32x16 s_acc[2];
#pragma unroll
    for (int r = 0; r < 16; ++r) { l_i[r] = 0.f; s_acc[0][r] = 0.f; s_acc[1][r] = 0.f; }

    for (int h = 0; h < 2; ++h) {
        const float* X = h ? hid : feat;
        const __bf16* Wkf = WKF + ((size_t)h * 96 << 8);
        const __bf16* Wv  = WV + ((size_t)(h * 16) * 64 << 8);

        // ---- A fragments: rows wrow+l5, k = u*16 + hi*8 (+j) ----
        bf16x8 a2[16];
#pragma unroll
        for (int u = 0; u < 16; ++u) {
            const float* p = X + ((size_t)(wrow + l5) << 8) + u * 16 + hi * 8;
            float4 x0 = *(const float4*)p;
            float4 x1 = *(const float4*)(p + 4);
            a2[u] = (bf16x8){ (__bf16)x0.x, (__bf16)x0.y, (__bf16)x0.z, (__bf16)x0.w,
                              (__bf16)x1.x, (__bf16)x1.y, (__bf16)x1.z, (__bf16)x1.w };
        }

        // ---- phase 1: scores vs folded K weights ----
        f32x16 acc1[3];
#pragma unroll
        for (int nt = 0; nt < 3; ++nt)
#pragma unroll
            for (int r = 0; r < 16; ++r) acc1[nt][r] = 0.f;
#pragma unroll
        for (int ks = 0; ks < 16; ++ks)
#pragma unroll
            for (int nt = 0; nt < 3; ++nt) {
                bf16x8 b = *(const bf16x8*)(Wkf + ((size_t)(nt * 32 + l5) << 8)
                                                + ks * 16 + hi * 8);
                acc1[nt] = MFMA32(a2[ks], b, acc1[nt]);
            }

        // epilogue: combine c-terms, exp, store wgt, accumulate l
#pragma unroll
        for (int g = 0; g < 4; ++g) {
            bf16x4 wv4;
#pragma unroll
            for (int j = 0; j < 4; ++j) {
                const int r = g * 4 + j;
                const int row32 = j + 8 * g + 4 * hi;
                float4 cm = cmd[wrow + row32];
                float e0, e1, t0[3], t1[3];
#pragma unroll
                for (int nt = 0; nt < 3; ++nt) {
                    e0 = acc1[nt][r];
                    e1 = __shfl_xor(e0, 16);
                    t0[nt] = low ? e0 : e1;
                    t1[nt] = low ? e1 : e0;
                }
                float sc = t0[0] + cm.x * t1[0] + cm.y * t0[1]
                                 + cm.z * t1[1] + cm.w * t0[2];
                float w = __expf(sc);
                wv4[j] = (__bf16)w;
                float ws = w;
                ws += __shfl_xor(ws, 1); ws += __shfl_xor(ws, 2);
                ws += __shfl_xor(ws, 4); ws += __shfl_xor(ws, 8);
                l_i[r] += ws;
            }
            if (low) *(bf16x4*)&WGT[wid][fl][8 * g + 4 * hi] = wv4;
        }

        // ---- phase 2: weighted V accumulation (16 f per half) ----
        for (int f2 = 0; f2 < 16; ++f2) {
            f32x16 acc2[2];
#pragma unroll
            for (int r = 0; r < 16; ++r) { acc2[0][r] = 0.f; acc2[1][r] = 0.f; }
            const __bf16* vb = Wv + ((size_t)(f2 * 64) << 8);
#pragma unroll
            for (int ks = 0; ks < 16; ++ks)
#pragma unroll
                for (int nt = 0; nt < 2; ++nt) {
                    bf16x8 b = *(const bf16x8*)(vb + ((size_t)(nt * 32 + l5) << 8)
                                                  + ks * 16 + hi * 8);
                    acc2[nt] = MFMA32(a2[ks], b, acc2[nt]);
                }
#pragma unroll
            for (int g = 0; g < 4; ++g) {
                bf16x4 wv = *(const bf16x4*)&WGT[wid][f2][8 * g + 4 * hi];
#pragma unroll
                for (int j = 0; j < 4; ++j) {
                    float w = (float)wv[j];
                    s_acc[0][g * 4 + j] += w * acc2[0][g * 4 + j];
                    s_acc[1][g * 4 + j] += w * acc2[1][g * 4 + j];
                }
            }
        }
    }

    // ---- epilogue: divide by l, store ----
#pragma unroll
    for (int g = 0; g < 4; ++g)
#pragma unroll
        for (int j = 0; j < 4; ++j) {
            const int r = g * 4 + j;
            float inv = 1.0f / l_i[r];
            size_t row = (size_t)(wrow + j + 8 * g + 4 * hi);
            out[(row << 6) + l5]      = s_acc[0][r] * inv;
            out[(row << 6) + 32 + l5] = s_acc[1][r] * inv;
        }
}

// ---------------------------------------------------------------------------
extern "C" void kernel_launch(void* const* d_in, const int* in_sizes, int n_in,
                              void* d_out, int out_size, void* d_ws, size_t ws_size,
                              hipStream_t stream)
{
    (void)in_sizes; (void)n_in; (void)out_size;
    const float* feature = (const float*)d_in[0];
    const float* hidden  = (const float*)d_in[1];
    const float* command = (const float*)d_in[2];
    const float* Wq      = (const float*)d_in[3];
    const float* Wkz     = (const float*)d_in[4];
    const float* Wkh     = (const float*)d_in[5];
    const float* Wvz     = (const float*)d_in[6];
    const float* Wvh     = (const float*)d_in[7];
    const float* gammaQ  = (const float*)d_in[8];
    const float* betaQ   = (const float*)d_in[9];
    const float* gammaK  = (const float*)d_in[10];
    const float* betaK   = (const float*)d_in[11];

    char* ws = (char*)d_ws;
    __bf16* WV   = (__bf16*)(ws + WS_WV);
    __bf16* WKF  = (__bf16*)(ws + WS_WKF);
    float*  G    = (float*)(ws + WS_G);
    float*  CS   = (float*)(ws + WS_CS);
    float*  CMDP = (float*)(ws + WS_CMDP);
    float*  Tj   = (float*)(ws + WS_T);
    float*  Uj   = (float*)(ws + WS_U);
    float*  Wq2  = (float*)(ws + WS_WQ2);
    float*  C0   = (float*)(ws + WS_C0);
    float*  Gp   = (float*)(ws + WS_GPART);
    float*  outp = (float*)d_out;

    const int tier = (ws_size >= (size_t)WS_NEED256) ? 2
                   : (ws_size >= (size_t)WS_NEED128) ? 1 : 0;

    hipMemsetAsync(ws + WS_CS, 0, 0x800, stream);
    if (tier == 0) hipMemsetAsync(ws + WS_G, 0, 0x80000, stream);

    prepV<<<512, 256, 0, stream>>>(Wvz, Wvh, WV);
    cmd_stats<<<64, 256, 0, stream>>>((const float4*)command, CMDP);
    if (tier == 2) {
        gram_kernel<<<256, 512, 0, stream>>>(feature, hidden, Gp, CS, 7, 16, 0);
        gram_reduce<<<512, 256, 0, stream>>>(Gp, G, 128);
    } else if (tier == 1) {
        gram_kernel<<<128, 512, 0, stream>>>(feature, hidden, Gp, CS, 6, 32, 0);
        gram_reduce<<<512, 256, 0, stream>>>(Gp, G, 64);
    } else {
        gram_kernel<<<256, 512, 0, stream>>>(feature, hidden, G, CS, 7, 16, 1);
    }
    rowstats<<<256, 256, 0, stream>>>(Wkz, Wkh, G, CS, Tj, Uj);
    finalize_kernel<<<1, 64, 0, stream>>>(Wq, gammaQ, betaQ, gammaK, betaK,
                                          CMDP, Tj, Uj, Wq2, C0);
    foldK<<<192, 256, 0, stream>>>(Wkz, Wkh, Wq2, C0, WKF);
    fused_attn<<<512, 256, 0, stream>>>(feature, hidden, (const float4*)command,
                                        WV, WKF, outp);
}

// Round 4
// 375.208 us; speedup vs baseline: 1.6128x; 1.6128x over previous
//
#include <hip/hip_runtime.h>
#include <hip/hip_bf16.h>
#include <math.h>

// ---------------------------------------------------------------------------
// FeatureAttnNet v4 for MI355X (gfx950)
//
// score[b,f] = Y0[b,f] + sum_c cmd[b,c]*Yc[b,f], Y = X @ WKfold^T (BN folded,
// additive BN term cancels in softmax). V GEMM fused with softmax weights.
// v4 fused_attn: 512 blocks (2/CU), wave=32 rows, A-frags in registers loaded
// once (X read once), B tiles LDS-staged with coalesced loads + xor swizzle,
// double-buffered (reg prefetch), 1 barrier per V-tile.
// Gram: NO atomics — bf16 partials in d_out (scratch before final write).
// ---------------------------------------------------------------------------

typedef float  f32x4   __attribute__((ext_vector_type(4)));
typedef float  f32x16  __attribute__((ext_vector_type(16)));
typedef __bf16 bf16x4  __attribute__((ext_vector_type(4)));
typedef __bf16 bf16x8  __attribute__((ext_vector_type(8)));

#define MFMA16(A, B, C) __builtin_amdgcn_mfma_f32_16x16x32_bf16((A), (B), (C), 0, 0, 0)
#define MFMA32(A, B, C) __builtin_amdgcn_mfma_f32_32x32x16_bf16((A), (B), (C), 0, 0, 0)

#define EPSV 1e-5f

// ---- workspace layout (bytes) ----
#define WS_WV    0x000000u   // 2048*256 bf16 = 1 MiB  [Wvz;Wvh]
#define WS_WKF   0x100000u   // 2*96*256 bf16 = 96 KiB folded K weights (zero-padded)
#define WS_G     0x120000u   // 2*256*256 f32 = 512 KiB
#define WS_CS    0x1A0000u   // 2*256 f32 colsums (zeroed)
#define WS_CMDP  0x1A0800u   // 32*14 f32 cmd partials
#define WS_T     0x1A1800u   // 2048 f32
#define WS_U     0x1A3800u   // 2048 f32
#define WS_WQ2   0x1A5800u   // 256 f32
#define WS_C0    0x1A5C00u   // 64 f32

// ---------------------------------------------------------------------------
// setup1: blk<128 -> gram partials (bf16 -> d_out); 128..383 -> prepV;
// 384..415 -> cmd stats.
__global__ __launch_bounds__(512, 2) void setup1(const float* __restrict__ feat,
        const float* __restrict__ hid, const float4* __restrict__ cmd,
        const float* __restrict__ Wvz, const float* __restrict__ Wvh,
        __bf16* __restrict__ WV, float* __restrict__ CMDP, float* __restrict__ CS,
        __bf16* __restrict__ Gp)
{
    __shared__ __bf16 T[256 * 40];
    __shared__ float sm[8][14];
    const int blk = blockIdx.x;
    const int tid = threadIdx.x;

    if (blk >= 384) {                     // ---- cmd stats: 32 blocks ----
        const int b2 = blk - 384;
        float v[14];
#pragma unroll
        for (int k = 0; k < 14; ++k) v[k] = 0.f;
#pragma unroll
        for (int i = 0; i < 4; ++i) {
            float4 c = cmd[(b2 * 4 + i) * 512 + tid];
            v[0] += c.x;  v[1] += c.y;  v[2] += c.z;  v[3] += c.w;
            v[4] += c.x*c.x; v[5] += c.x*c.y; v[6] += c.x*c.z; v[7] += c.x*c.w;
            v[8] += c.y*c.y; v[9] += c.y*c.z; v[10] += c.y*c.w;
            v[11] += c.z*c.z; v[12] += c.z*c.w; v[13] += c.w*c.w;
        }
#pragma unroll
        for (int k = 0; k < 14; ++k) {
            float s = v[k];
#pragma unroll
            for (int off = 32; off; off >>= 1) s += __shfl_xor(s, off);
            if ((tid & 63) == 0) sm[tid >> 6][k] = s;
        }
        __syncthreads();
        if (tid < 14) {
            float s = 0.f;
#pragma unroll
            for (int w = 0; w < 8; ++w) s += sm[w][tid];
            CMDP[b2 * 14 + tid] = s;
        }
        return;
    }
    if (blk >= 128) {                     // ---- prepV: 256 blocks ----
        int t = (blk - 128) * 512 + tid;
        int e = t * 4;
        const float* src = (e < 262144) ? (Wvz + e) : (Wvh + (e - 262144));
        float4 a = *(const float4*)src;
        bf16x4 vv = { (__bf16)a.x, (__bf16)a.y, (__bf16)a.z, (__bf16)a.w };
        *(bf16x4*)(WV + e) = vv;
        return;
    }

    // ---- gram: 128 blocks = 2 mats x 64 chunks x 1024 rows ----
    const int mat  = blk >> 6;
    const int chunk = blk & 63;
    const float* X = mat ? hid : feat;
    float* cs = CS + mat * 256;
    const int k0   = chunk * 1024;
    const int wid  = tid >> 6, lane = tid & 63, quad = lane >> 4, l15 = lane & 15;
    const int c    = tid & 255;
    const int t8   = tid >> 8;

    f32x4 acc[2][16];
#pragma unroll
    for (int mt = 0; mt < 2; ++mt)
#pragma unroll
        for (int nt = 0; nt < 16; ++nt) acc[mt][nt] = (f32x4){0.f, 0.f, 0.f, 0.f};

    float clsum = 0.f;
    for (int it = 0; it < 32; ++it) {
        __syncthreads();
        const int kb = k0 + it * 32;
#pragma unroll
        for (int i = 0; i < 16; ++i) {
            int k = t8 + 2 * i;
            float x = X[(size_t)(kb + k) * 256 + c];
            clsum += x;
            T[c * 40 + k] = (__bf16)x;
        }
        __syncthreads();
        bf16x8 a0 = *(const bf16x8*)&T[(wid * 32 +      l15) * 40 + quad * 8];
        bf16x8 a1 = *(const bf16x8*)&T[(wid * 32 + 16 + l15) * 40 + quad * 8];
#pragma unroll
        for (int nt = 0; nt < 16; ++nt) {
            bf16x8 b = *(const bf16x8*)&T[(nt * 16 + l15) * 40 + quad * 8];
            acc[0][nt] = MFMA16(a0, b, acc[0][nt]);
            acc[1][nt] = MFMA16(a1, b, acc[1][nt]);
        }
    }
    atomicAdd(&cs[c], clsum);             // 512 addrs, 128-way — cheap
    __bf16* outp = Gp + (size_t)blk * 65536;
#pragma unroll
    for (int mt = 0; mt < 2; ++mt)
#pragma unroll
        for (int nt = 0; nt < 16; ++nt)
#pragma unroll
            for (int r = 0; r < 4; ++r) {
                int gi = wid * 32 + mt * 16 + quad * 4 + r;
                int gj = nt * 16 + l15;
                outp[gi * 256 + gj] = (__bf16)acc[mt][nt][r];
            }
}

// ---------------------------------------------------------------------------
__global__ void gram_reduce(const __bf16* __restrict__ Gp, float* __restrict__ G)
{
    int o = blockIdx.x * 256 + threadIdx.x;      // 512 x 256 = 131072
    int mat = o >> 16, e = o & 65535;
    const __bf16* p = Gp + (size_t)mat * 64 * 65536 + e;
    float s = 0.f;
#pragma unroll 8
    for (int c = 0; c < 64; ++c) s += (float)p[(size_t)c * 65536];
    G[o] = s;
}

// ---------------------------------------------------------------------------
__global__ void rowstats(const float* __restrict__ Wkz, const float* __restrict__ Wkh,
        const float* __restrict__ G, const float* __restrict__ CS,
        float* __restrict__ Tout, float* __restrict__ Uout)
{
    const int blk = blockIdx.x;               // 256 blocks
    const int mat = blk >> 7, jg = blk & 127;
    const float* Wsrc = (mat ? Wkh : Wkz) + (size_t)jg * 8 * 256;
    const float* Gm = G + (size_t)mat * 65536;
    const float* cs = CS + mat * 256;
    __shared__ float wlT[256 * 8];
    __shared__ float red[4][16];
    const int tid = threadIdx.x, wid = tid >> 6, lane = tid & 63;
#pragma unroll
    for (int jj = 0; jj < 8; ++jj) wlT[tid * 8 + jj] = Wsrc[jj * 256 + tid];
    __syncthreads();
    float inner[8];
#pragma unroll
    for (int jj = 0; jj < 8; ++jj) inner[jj] = 0.f;
    for (int r = 0; r < 256; ++r) {
        float g = Gm[r * 256 + tid];
        float4 w0 = *(const float4*)&wlT[r * 8];
        float4 w1 = *(const float4*)&wlT[r * 8 + 4];
        inner[0] = fmaf(w0.x, g, inner[0]); inner[1] = fmaf(w0.y, g, inner[1]);
        inner[2] = fmaf(w0.z, g, inner[2]); inner[3] = fmaf(w0.w, g, inner[3]);
        inner[4] = fmaf(w1.x, g, inner[4]); inner[5] = fmaf(w1.y, g, inner[5]);
        inner[6] = fmaf(w1.z, g, inner[6]); inner[7] = fmaf(w1.w, g, inner[7]);
    }
    float cst = cs[tid];
#pragma unroll
    for (int jj = 0; jj < 8; ++jj) {
        float wme = wlT[tid * 8 + jj];
        float p = wme * inner[jj];
        float u = wme * cst;
#pragma unroll
        for (int off = 32; off; off >>= 1) { p += __shfl_xor(p, off); u += __shfl_xor(u, off); }
        if (lane == 0) { red[wid][jj] = p; red[wid][jj + 8] = u; }
    }
    __syncthreads();
    if (tid < 16) {
        float s = red[0][tid] + red[1][tid] + red[2][tid] + red[3][tid];
        int jj = tid & 7;
        int j = mat * 1024 + jg * 8 + jj;
        if (tid < 8) Tout[j] = s; else Uout[j] = s;
    }
}

// ---------------------------------------------------------------------------
__global__ void finalize_kernel(const float* __restrict__ Wq,
        const float* __restrict__ gQ, const float* __restrict__ bQ,
        const float* __restrict__ gK, const float* __restrict__ bK,
        const float* __restrict__ CMDP, const float* __restrict__ T,
        const float* __restrict__ U, float* __restrict__ Wq2, float* __restrict__ C0)
{
    __shared__ float s14[14];
    const int d = threadIdx.x;
    if (d < 14) {
        float s = 0.f;
        for (int b = 0; b < 32; ++b) s += CMDP[b * 14 + d];
        s14[d] = s;
    }
    __syncthreads();
    float s4[4] = { s14[0], s14[1], s14[2], s14[3] };
    float gc[4][4];
    gc[0][0] = s14[4];
    gc[0][1] = gc[1][0] = s14[5];
    gc[0][2] = gc[2][0] = s14[6];
    gc[0][3] = gc[3][0] = s14[7];
    gc[1][1] = s14[8];
    gc[1][2] = gc[2][1] = s14[9];
    gc[1][3] = gc[3][1] = s14[10];
    gc[2][2] = s14[11];
    gc[2][3] = gc[3][2] = s14[12];
    gc[3][3] = s14[13];
    float wq[4];
#pragma unroll
    for (int c = 0; c < 4; ++c) wq[c] = Wq[d * 4 + c];
    const float invB = 1.0f / 65536.0f;
    float mQ = (wq[0]*s4[0] + wq[1]*s4[1] + wq[2]*s4[2] + wq[3]*s4[3]) * invB;
    float eq2 = 0.f;
#pragma unroll
    for (int c = 0; c < 4; ++c)
#pragma unroll
        for (int c2 = 0; c2 < 4; ++c2) eq2 += wq[c] * wq[c2] * gc[c][c2];
    eq2 *= invB;
    float vQ  = eq2 - mQ * mQ;
    float aQ  = gQ[d] / sqrtf(vQ + EPSV);
    float bQv = bQ[d] - mQ * aQ;
    float S2 = 0.f, S1 = 0.f;
#pragma unroll
    for (int f = 0; f < 32; ++f) { S2 += T[f * 64 + d]; S1 += U[f * 64 + d]; }
    const float invBF = 1.0f / (65536.0f * 32.0f);
    float e2 = S2 * invBF, mK = S1 * invBF;
    float vK = e2 - mK * mK;
    float aK = gK[d] / sqrtf(vK + EPSV);
    float c1 = aQ * aK * 0.125f;      // 1/sqrt(64) folded in
    C0[d] = bQv * aK * 0.125f;
#pragma unroll
    for (int c = 0; c < 4; ++c) Wq2[d * 4 + c] = c1 * wq[c];
}

// ---------------------------------------------------------------------------
// WKF[h][r = c*16 + fl][k] = sum_d coef_c[d]*W_h[fl*64+d][k]; rows 80..95 = 0.
__global__ void foldK(const float* __restrict__ Wkz, const float* __restrict__ Wkh,
                      const float* __restrict__ Wq2, const float* __restrict__ C0,
                      __bf16* __restrict__ WKF)
{
    const int blk = blockIdx.x;               // 192
    const int h = blk / 96, rr = blk % 96;
    const int k = threadIdx.x;
    float s = 0.f;
    if (rr < 80) {
        const int c = rr >> 4, fl = rr & 15;
        const float* Wsrc = (h ? Wkh : Wkz) + (size_t)fl * 64 * 256;
        for (int d = 0; d < 64; ++d) {
            float coef = (c == 0) ? C0[d] : Wq2[d * 4 + (c - 1)];
            s = fmaf(coef, Wsrc[d * 256 + k], s);
        }
    }
    WKF[(size_t)(h * 96 + rr) * 256 + k] = (__bf16)s;
}

// ---------------------------------------------------------------------------
// fused_attn v4: 512 blocks x 256 threads; wave = 32 rows; LDS-staged B with
// xor swizzle; dbuf V tiles; 1 barrier per tile; X read once.
__global__ __launch_bounds__(256, 2) void fused_attn(
        const float* __restrict__ feat, const float* __restrict__ hid,
        const float4* __restrict__ cmd, const __bf16* __restrict__ WV,
        const __bf16* __restrict__ WKF, float* __restrict__ out)
{
    __shared__ __bf16 BUF[32768];             // 64 KiB (dbuf 2x32KB / p1 48KB)
    __shared__ __bf16 WGTs[16 * 128];         // 4 KiB, [f][row]
    const int tid  = threadIdx.x;
    const int wid  = tid >> 6, lane = tid & 63;
    const int l5   = lane & 31, hi = lane >> 5;
    const int fl   = l5 & 15;
    const bool low = (l5 < 16);
    const int wrow = (blockIdx.x << 7) + (wid << 5);   // wave's 32 rows

    float l_i[16];
    f32x16 s_acc[2];
#pragma unroll
    for (int r = 0; r < 16; ++r) { l_i[r] = 0.f; s_acc[0][r] = 0.f; s_acc[1][r] = 0.f; }

    bf16x8 st[8];

    for (int h = 0; h < 2; ++h) {
        const float* X = h ? hid : feat;
        const __bf16* Wkf = WKF + ((size_t)h * 96 << 8);

        // ---- A fragments (32x32x16): row wrow+l5, k = u*16 + hi*8 + j ----
        bf16x8 a2[16];
#pragma unroll
        for (int u = 0; u < 16; ++u) {
            const float* p = X + ((size_t)(wrow + l5) << 8) + u * 16 + hi * 8;
            float4 x0 = *(const float4*)p;
            float4 x1 = *(const float4*)(p + 4);
            a2[u] = (bf16x8){ (__bf16)x0.x, (__bf16)x0.y, (__bf16)x0.z, (__bf16)x0.w,
                              (__bf16)x1.x, (__bf16)x1.y, (__bf16)x1.z, (__bf16)x1.w };
        }

        // ---- phase 1: stage WKF (96 rows) and compute scores ----
        __syncthreads();                      // prior readers of BUF done
#pragma unroll
        for (int i = 0; i < 12; ++i) {
            int cc = tid + i * 256;           // 3072 chunks
            int n = cc >> 5, k8 = cc & 31;
            bf16x8 v = *(const bf16x8*)(Wkf + n * 256 + k8 * 8);
            *(bf16x8*)&BUF[n * 256 + ((k8 ^ (n & 7)) << 3)] = v;
        }
        __syncthreads();

        f32x16 acc1[3];
#pragma unroll
        for (int nt = 0; nt < 3; ++nt)
#pragma unroll
            for (int r = 0; r < 16; ++r) acc1[nt][r] = 0.f;
#pragma unroll
        for (int ks = 0; ks < 16; ++ks)
#pragma unroll
            for (int nt = 0; nt < 3; ++nt) {
                int n = nt * 32 + l5;
                bf16x8 b = *(const bf16x8*)&BUF[n * 256 + (((ks * 2 + hi) ^ (n & 7)) << 3)];
                acc1[nt] = MFMA32(a2[ks], b, acc1[nt]);
            }

        // epilogue: combine c-terms, exp, store wgt, accumulate l
#pragma unroll
        for (int g = 0; g < 4; ++g) {
            bf16x4 wv4;
#pragma unroll
            for (int j = 0; j < 4; ++j) {
                const int r = g * 4 + j;
                const int row32 = j + 8 * g + 4 * hi;
                float4 cm = cmd[wrow + row32];
                float e0, e1, t0[3], t1[3];
#pragma unroll
                for (int nt = 0; nt < 3; ++nt) {
                    e0 = acc1[nt][r];
                    e1 = __shfl_xor(e0, 16);
                    t0[nt] = low ? e0 : e1;
                    t1[nt] = low ? e1 : e0;
                }
                float sc = t0[0] + cm.x * t1[0] + cm.y * t0[1]
                                 + cm.z * t1[1] + cm.w * t0[2];
                float w = __expf(sc);
                wv4[j] = (__bf16)w;
                float ws = w;
                ws += __shfl_xor(ws, 1); ws += __shfl_xor(ws, 2);
                ws += __shfl_xor(ws, 4); ws += __shfl_xor(ws, 8);
                l_i[r] += ws;
            }
            if (low) *(bf16x4*)&WGTs[fl * 128 + (wid << 5) + 8 * g + 4 * hi] = wv4;
        }

        // preload first V tile of this half (h=0 only; h=1 carried from prev)
        if (h == 0) {
            const __bf16* base = WV;          // tile 0
#pragma unroll
            for (int i = 0; i < 8; ++i) {
                int cc = tid + i * 256;
                int n = cc >> 5, k8 = cc & 31;
                st[i] = *(const bf16x8*)(base + n * 256 + k8 * 8);
            }
        }
        __syncthreads();                      // phase-1 BUF reads done

        // ---- phase 2: 16 V tiles, dbuf, 1 barrier each ----
        for (int f2 = 0; f2 < 16; ++f2) {
            const int bufsel = (f2 & 1) << 14;
#pragma unroll
            for (int i = 0; i < 8; ++i) {
                int cc = tid + i * 256;
                int n = cc >> 5, k8 = cc & 31;
                *(bf16x8*)&BUF[bufsel + n * 256 + ((k8 ^ (n & 7)) << 3)] = st[i];
            }
            __syncthreads();
            const int g2 = h * 16 + f2 + 1;   // next global tile
            if (g2 < 32) {
                const __bf16* base = WV + ((size_t)g2 << 14);
#pragma unroll
                for (int i = 0; i < 8; ++i) {
                    int cc = tid + i * 256;
                    int n = cc >> 5, k8 = cc & 31;
                    st[i] = *(const bf16x8*)(base + n * 256 + k8 * 8);
                }
            }
            f32x16 acc2[2];
#pragma unroll
            for (int r = 0; r < 16; ++r) { acc2[0][r] = 0.f; acc2[1][r] = 0.f; }
#pragma unroll
            for (int ks = 0; ks < 16; ++ks)
#pragma unroll
                for (int nt = 0; nt < 2; ++nt) {
                    int n = nt * 32 + l5;
                    bf16x8 b = *(const bf16x8*)&BUF[bufsel + n * 256
                                                    + (((ks * 2 + hi) ^ (n & 7)) << 3)];
                    acc2[nt] = MFMA32(a2[ks], b, acc2[nt]);
                }
#pragma unroll
            for (int g = 0; g < 4; ++g) {
                bf16x4 wv = *(const bf16x4*)&WGTs[f2 * 128 + (wid << 5) + 8 * g + 4 * hi];
#pragma unroll
                for (int j = 0; j < 4; ++j) {
                    float w = (float)wv[j];
                    s_acc[0][g * 4 + j] += w * acc2[0][g * 4 + j];
                    s_acc[1][g * 4 + j] += w * acc2[1][g * 4 + j];
                }
            }
        }
    }

    // ---- epilogue: divide by l, store ----
#pragma unroll
    for (int g = 0; g < 4; ++g)
#pragma unroll
        for (int j = 0; j < 4; ++j) {
            const int r = g * 4 + j;
            float inv = 1.0f / l_i[r];
            size_t row = (size_t)(wrow + j + 8 * g + 4 * hi);
            out[(row << 6) + l5]      = s_acc[0][r] * inv;
            out[(row << 6) + 32 + l5] = s_acc[1][r] * inv;
        }
}

// ---------------------------------------------------------------------------
extern "C" void kernel_launch(void* const* d_in, const int* in_sizes, int n_in,
                              void* d_out, int out_size, void* d_ws, size_t ws_size,
                              hipStream_t stream)
{
    (void)in_sizes; (void)n_in; (void)out_size; (void)ws_size;
    const float* feature = (const float*)d_in[0];
    const float* hidden  = (const float*)d_in[1];
    const float* command = (const float*)d_in[2];
    const float* Wq      = (const float*)d_in[3];
    const float* Wkz     = (const float*)d_in[4];
    const float* Wkh     = (const float*)d_in[5];
    const float* Wvz     = (const float*)d_in[6];
    const float* Wvh     = (const float*)d_in[7];
    const float* gammaQ  = (const float*)d_in[8];
    const float* betaQ   = (const float*)d_in[9];
    const float* gammaK  = (const float*)d_in[10];
    const float* betaK   = (const float*)d_in[11];

    char* ws = (char*)d_ws;
    __bf16* WV   = (__bf16*)(ws + WS_WV);
    __bf16* WKF  = (__bf16*)(ws + WS_WKF);
    float*  G    = (float*)(ws + WS_G);
    float*  CS   = (float*)(ws + WS_CS);
    float*  CMDP = (float*)(ws + WS_CMDP);
    float*  Tj   = (float*)(ws + WS_T);
    float*  Uj   = (float*)(ws + WS_U);
    float*  Wq2  = (float*)(ws + WS_WQ2);
    float*  C0   = (float*)(ws + WS_C0);
    float*  outp = (float*)d_out;
    __bf16* Gp   = (__bf16*)d_out;            // 16 MB scratch before final write

    hipMemsetAsync(ws + WS_CS, 0, 0x800, stream);
    setup1<<<416, 512, 0, stream>>>(feature, hidden, (const float4*)command,
                                    Wvz, Wvh, WV, CMDP, CS, Gp);
    gram_reduce<<<512, 256, 0, stream>>>(Gp, G);
    rowstats<<<256, 256, 0, stream>>>(Wkz, Wkh, G, CS, Tj, Uj);
    finalize_kernel<<<1, 64, 0, stream>>>(Wq, gammaQ, betaQ, gammaK, betaK,
                                          CMDP, Tj, Uj, Wq2, C0);
    foldK<<<192, 256, 0, stream>>>(Wkz, Wkh, Wq2, C0, WKF);
    fused_attn<<<512, 256, 0, stream>>>(feature, hidden, (const float4*)command,
                                        WV, WKF, outp);
}